// Round 8
// baseline (223.566 us; speedup 1.0000x reference)
//
#include <hip/hip_runtime.h>
#include <stdint.h>

// Fused Swin window attention for MI355X (gfx950) — R8 = R7 @ 8 waves/SIMD.
// B=4096 windows, N=64 tokens, C=128, H=4 heads, D=32.
// One block = one window; 512 threads = 8 waves; wave = (head h, token-half u).
// bf16 MFMA 16x16x32, f32 accum.
//
// R7 result: spill-free (WRITE 131MB clean), VGPR=48, but launch_bounds(512,4)
// caps residency at 2 blocks/CU = 16 waves/CU (50%) -> latency-bound at 43%
// occupancy, dur 130us. R8's single change: launch_bounds(512,8) -> 4 blocks/CU
// = 32 waves/CU (100% cap). VGPR budget 512/8=64 >= measured 48 -> no spill.
//
// Structure (validated R7): one-pass QKV for 32 tokens/wave (#pragma unroll 1
// on ks loop), K/V exchanged as 1KB lane-linear b128 frags via LDS, S^T = K Q^T
// with bias*log2e as acc-init, no-max exp2 softmax (P unnormalized, 1/sum in
// O rescale), O^T = V^T P^T, proj via O-frag exchange.
//
// LDS (32 KB):
//   [0,16K):   x bf16 [64 tok][256B] swz; after barrier2 aliased by vbuf
//              (V^T frags [h][u][dt] x 1KB)
//   [16K,32K): kbuf K-frags [h][mt] x 1KB; after barrier3 aliased by obuf
//              (O^T frags [h][mt] x 1KB)
// d_ws: wq bf16 @0 (96KB, Q-section pre-scaled by SCALE*log2e) |
//       wp bf16 @98304 (32KB) | bias_full f32 [H][64][64] @131072 (64KB, *log2e)

typedef __attribute__((ext_vector_type(4))) float        f32x4;
typedef __attribute__((ext_vector_type(8))) __bf16       bf16x8;
typedef __attribute__((ext_vector_type(4))) unsigned int u32x4;

#define DEV static __device__ __forceinline__

DEV unsigned short f2bf(float f) {          // f32 -> bf16 RNE (prep kernel only)
  unsigned int u = __float_as_uint(f);
  u += 0x7FFFu + ((u >> 16) & 1u);
  return (unsigned short)(u >> 16);
}

DEV unsigned int pk2(float a, float b) {    // packed bf16x2 via compiler casts
  __bf16 x = (__bf16)a, y = (__bf16)b;
  unsigned short ux = __builtin_bit_cast(unsigned short, x);
  unsigned short uy = __builtin_bit_cast(unsigned short, y);
  return (unsigned int)ux | ((unsigned int)uy << 16);
}

// Swizzled LDS byte address for x (XOR multiple of 16 keeps 16B alignment).
DEV int xaddr(int r, int cb) { return r*256 + (cb ^ ((r & 7) << 4)); }  // 256B rows

DEV f32x4 mfma16(bf16x8 a, bf16x8 b, f32x4 c) {
  return __builtin_amdgcn_mfma_f32_16x16x32_bf16(a, b, c, 0, 0, 0);
}

// In-register transpose (validated R3-R7): two C/D tiles of a 32-row x 16-col
// matrix M (t0 = rows 0..15, t1 = rows 16..31) -> fragment where lane (lq,l15)
// holds M[lq*8+i][l15], i=0..7, as bf16x8. Serves as B-frag of M (k=rows) and
// equally as A-frag of M^T.
DEV bf16x8 xpose(f32x4 t0, f32x4 t1, int idxA, int idxB, bool hi) {
  int a0 = (int)pk2(t0[0], t0[1]), a1 = (int)pk2(t0[2], t0[3]);
  int b0 = (int)pk2(t1[0], t1[1]), b1 = (int)pk2(t1[2], t1[3]);
  int w0A = __builtin_amdgcn_ds_bpermute(idxA, a0);
  int w0B = __builtin_amdgcn_ds_bpermute(idxA, b0);
  int w1A = __builtin_amdgcn_ds_bpermute(idxA, a1);
  int w1B = __builtin_amdgcn_ds_bpermute(idxA, b1);
  int w2A = __builtin_amdgcn_ds_bpermute(idxB, a0);
  int w2B = __builtin_amdgcn_ds_bpermute(idxB, b0);
  int w3A = __builtin_amdgcn_ds_bpermute(idxB, a1);
  int w3B = __builtin_amdgcn_ds_bpermute(idxB, b1);
  u32x4 u;
  u[0] = (unsigned)(hi ? w0B : w0A);
  u[1] = (unsigned)(hi ? w1B : w1A);
  u[2] = (unsigned)(hi ? w2B : w2A);
  u[3] = (unsigned)(hi ? w3B : w3A);
  return __builtin_bit_cast(bf16x8, u);
}

// Pack weights into the shared A/B fragment order; Q-section pre-scaled by
// SCALE*log2e; bias_full pre-scaled by log2e (softmax uses exp2 directly).
// Frag: lane l holds W[k=ks*32+(l>>4)*8+i][col=nt*16+(l&15)], i=0..7.
__global__ void prep_kernel(const float* __restrict__ qkv_w, const float* __restrict__ proj_w,
                            const float* __restrict__ bias_table,
                            unsigned short* __restrict__ wq, unsigned short* __restrict__ wp,
                            float* __restrict__ bias_full) {
  const float SCALE_LOG2E = 0.17677669529663687f * 1.4426950408889634f;
  const float LOG2E = 1.4426950408889634f;
  int idx = blockIdx.x * 256 + threadIdx.x;
  if (idx < 49152) {                                    // qkv_w (128 x 384)
    int i = idx & 7, lane = (idx >> 3) & 63, ks = (idx >> 9) & 3, nt = idx >> 11;
    int k = ks*32 + (lane >> 4)*8 + i;
    int col = nt*16 + (lane & 15);
    float v = qkv_w[k*384 + col];
    if (nt < 8) v *= SCALE_LOG2E;                       // Q section pre-scaled
    wq[idx] = f2bf(v);
  } else if (idx < 65536) {                             // proj_w (128 x 128)
    int t = idx - 49152;
    int i = t & 7, lane = (t >> 3) & 63, ks = (t >> 9) & 3, nt = t >> 11;
    int k = ks*32 + (lane >> 4)*8 + i;
    int col = nt*16 + (lane & 15);
    wp[t] = f2bf(proj_w[k*128 + col]);
  } else if (idx < 81920) {                             // bias_full[h][q][k] * log2e
    int t = idx - 65536;
    int h = t >> 12, q = (t >> 6) & 63, kk = t & 63;
    int ri = q >> 3, ci = q & 7, rj = kk >> 3, cj = kk & 7;
    bias_full[t] = bias_table[((ri - rj + 7)*15 + (ci - cj + 7))*4 + h] * LOG2E;
  }
}

__global__ __launch_bounds__(512, 8) void fused_kernel(
    const float* __restrict__ x, const float* __restrict__ qkv_b, const float* __restrict__ proj_b,
    const unsigned short* __restrict__ wq, const unsigned short* __restrict__ wp,
    const float* __restrict__ bias_full, float* __restrict__ out)
{
  __shared__ __align__(16) char lds[32768];
  const int b    = blockIdx.x;
  const int tid  = threadIdx.x;
  const int lane = tid & 63;
  const int w2   = tid >> 6;       // wave id 0..7
  const int h    = w2 >> 1;        // head
  const int u    = w2 & 1;         // token half (tokens u*32 .. u*32+31)
  const int l15  = lane & 15;
  const int lq   = lane >> 4;      // quarter-wave 0..3
  const float SCALE_LOG2E = 0.17677669529663687f * 1.4426950408889634f;
  const int  idxA = (((2*lq) & 3)*16 + l15) * 4;   // bpermute byte indices
  const int  idxB = idxA + 64;
  const bool hi   = lq >= 2;
  char* fbK = lds + 16384;   // kbuf, later obuf

  // ---------- stage x -> [0,16K) as bf16 (swizzled) ----------
  {
    const float4* x4 = (const float4*)(x + (size_t)b * 8192);
    #pragma unroll
    for (int it = 0; it < 4; ++it) {
      int f4 = it*512 + tid;                 // 0..2047
      int r = f4 >> 5, c4 = f4 & 31;
      float4 v = x4[f4];
      *(uint2*)(lds + xaddr(r, c4*8)) = make_uint2(pk2(v.x, v.y), pk2(v.z, v.w));
    }
  }
  __syncthreads();                           // barrier 1

  // ---------- one-pass QKV for this wave's 32 tokens (m-tiles 2u, 2u+1) ----------
  bf16x8 qf[2], kfl[2], vfl[2];
  {
    f32x4 qacc[2][2], kacc[2][2], vacc[2][2];
    #pragma unroll
    for (int t = 0; t < 2; ++t) {
      float4 bq = *(const float4*)(qkv_b +       h*32 + t*16 + lq*4);
      float4 bk = *(const float4*)(qkv_b + 128 + h*32 + t*16 + lq*4);
      f32x4 qi = {bq.x*SCALE_LOG2E, bq.y*SCALE_LOG2E, bq.z*SCALE_LOG2E, bq.w*SCALE_LOG2E};
      f32x4 ki = {bk.x, bk.y, bk.z, bk.w};
      #pragma unroll
      for (int i = 0; i < 2; ++i) { qacc[t][i] = qi; kacc[t][i] = ki; }
    }
    #pragma unroll
    for (int dt = 0; dt < 2; ++dt) {
      float bv = qkv_b[256 + h*32 + dt*16 + l15];
      #pragma unroll
      for (int i = 0; i < 2; ++i) vacc[i][dt] = (f32x4){bv, bv, bv, bv};
    }
    #pragma unroll 1                          // keep per-iteration liveness low
    for (int ks = 0; ks < 4; ++ks) {
      bf16x8 xfr[2];   // x[tok=(2u+i)*16+l15][c=ks*32+lq*8+i8]
      #pragma unroll
      for (int i = 0; i < 2; ++i)
        xfr[i] = *(const bf16x8*)(lds + xaddr((2*u + i)*16 + l15, ks*64 + lq*16));
      #pragma unroll
      for (int t = 0; t < 2; ++t) {
        bf16x8 wfq = *(const bf16x8*)((const char*)wq + (((2*h + t)*4      + ks)*64 + lane)*16);
        bf16x8 wfk = *(const bf16x8*)((const char*)wq + (((8 + 2*h + t)*4  + ks)*64 + lane)*16);
        bf16x8 wfv = *(const bf16x8*)((const char*)wq + (((16 + 2*h + t)*4 + ks)*64 + lane)*16);
        #pragma unroll
        for (int i = 0; i < 2; ++i) {
          qacc[t][i] = mfma16(wfq, xfr[i], qacc[t][i]);   // Q^T tile (feat t, tok 2u+i)
          kacc[t][i] = mfma16(wfk, xfr[i], kacc[t][i]);   // K^T tile
          vacc[i][t] = mfma16(xfr[i], wfv, vacc[i][t]);   // V  tile (tok 2u+i, d t)
        }
      }
    }
    #pragma unroll
    for (int i = 0; i < 2; ++i) {
      qf[i]  = xpose(qacc[0][i], qacc[1][i], idxA, idxB, hi);  // B-frag Q^T[d][q]
      kfl[i] = xpose(kacc[0][i], kacc[1][i], idxA, idxB, hi);  // A-frag K[key][d]
    }
    #pragma unroll
    for (int dt = 0; dt < 2; ++dt)
      vfl[dt] = xpose(vacc[0][dt], vacc[1][dt], idxA, idxB, hi); // A-frag V^T, toks u*32..+31
  }

  // K frags -> kbuf (fresh region; lane-linear b128, conflict-free)
  #pragma unroll
  for (int i = 0; i < 2; ++i)
    *(bf16x8*)(fbK + (h*4 + 2*u + i)*1024 + lane*16) = kfl[i];
  __syncthreads();                           // barrier 2: x dead, kbuf visible

  // V frags -> vbuf (aliases x region, safe after barrier 2)
  #pragma unroll
  for (int dt = 0; dt < 2; ++dt)
    *(bf16x8*)(lds + ((h*2 + u)*2 + dt)*1024 + lane*16) = vfl[dt];

  // ---------- S^T = K Q^T (all 64 keys x own 32 q), exp2 softmax, P frags ----------
  bf16x8 pf[2][2];   // [ks][m]: B-frag P^T, keys ks*32.., q-tile 2u+m
  float inv_[2];
  {
    bf16x8 kf[4];
    #pragma unroll
    for (int n = 0; n < 4; ++n)
      kf[n] = *(const bf16x8*)(fbK + (h*4 + n)*1024 + lane*16);
    const float* bh = bias_full + h*4096;
    f32x4 s[4][2];   // tile (key n, q m): row=key=n*16+lq*4+j, col=q=(2u+m)*16+l15
    #pragma unroll
    for (int n = 0; n < 4; ++n)
      #pragma unroll
      for (int m = 0; m < 2; ++m) {
        float4 b4 = *(const float4*)(bh + ((2*u + m)*16 + l15)*64 + n*16 + lq*4);
        f32x4 si = {b4.x, b4.y, b4.z, b4.w};
        s[n][m] = mfma16(kf[n], qf[m], si);
      }
    // no-max softmax in base-2 (validated R3-R7); P unnormalized, 1/sum folded
    // into the O rescale.
    #pragma unroll
    for (int m = 0; m < 2; ++m) {
      float sum = 0.f;
      #pragma unroll
      for (int n = 0; n < 4; ++n)
        #pragma unroll
        for (int j = 0; j < 4; ++j) {
          float p = exp2f(s[n][m][j]);
          s[n][m][j] = p;
          sum += p;
        }
      sum += __shfl_xor(sum, 16);
      sum += __shfl_xor(sum, 32);
      inv_[m] = __fdividef(1.f, sum);
    }
    #pragma unroll
    for (int ks = 0; ks < 2; ++ks)
      #pragma unroll
      for (int m = 0; m < 2; ++m)
        pf[ks][m] = xpose(s[2*ks][m], s[2*ks + 1][m], idxA, idxB, hi);
  }
  __syncthreads();                           // barrier 3: vbuf visible, kbuf reads done

  // ---------- O^T = V^T P^T (V frags from vbuf) ----------
  f32x4 o[2][2];   // tile (d dt, q m): row=d=dt*16+lq*4+j, col=q=(2u+m)*16+l15
  #pragma unroll
  for (int dt = 0; dt < 2; ++dt)
    #pragma unroll
    for (int m = 0; m < 2; ++m) o[dt][m] = (f32x4){0.f, 0.f, 0.f, 0.f};
  #pragma unroll
  for (int up = 0; up < 2; ++up) {           // key half = token half of V
    #pragma unroll
    for (int dt = 0; dt < 2; ++dt) {
      bf16x8 vf = *(const bf16x8*)(lds + ((h*2 + up)*2 + dt)*1024 + lane*16);
      #pragma unroll
      for (int m = 0; m < 2; ++m)
        o[dt][m] = mfma16(vf, pf[up][m], o[dt][m]);
    }
  }

  // rescale, xpose into proj B-frags, exchange (obuf aliases kbuf; all kbuf
  // reads completed before barrier 3)
  #pragma unroll
  for (int m = 0; m < 2; ++m) {
    f32x4 o0 = o[0][m], o1 = o[1][m];
    #pragma unroll
    for (int j = 0; j < 4; ++j) { o0[j] *= inv_[m]; o1[j] *= inv_[m]; }
    bf16x8 frg = xpose(o0, o1, idxA, idxB, hi);  // B-frag O^T: [ch=h*32+lq*8+i][q=l15]
    *(bf16x8*)(fbK + (h*4 + 2*u + m)*1024 + lane*16) = frg;
  }
  __syncthreads();                           // barrier 4: obuf visible

  // ---------- proj quarter: tokens (w2&3)*16.., features (w2>>2)*64.. ----------
  const int mt = w2 & 3;                     // token tile
  const int fh = w2 >> 2;                    // feature half
  bf16x8 ofr[4];
  #pragma unroll
  for (int hh = 0; hh < 4; ++hh)
    ofr[hh] = *(const bf16x8*)(fbK + (hh*4 + mt)*1024 + lane*16);

  f32x4 pacc[4];   // OUT^T tiles (feature fh*4+tp, tok tile mt)
  #pragma unroll
  for (int tp = 0; tp < 4; ++tp) {
    float4 pb4 = *(const float4*)(proj_b + (fh*4 + tp)*16 + lq*4);
    pacc[tp] = (f32x4){pb4.x, pb4.y, pb4.z, pb4.w};
  }
  #pragma unroll
  for (int hh = 0; hh < 4; ++hh)
    #pragma unroll
    for (int tp = 0; tp < 4; ++tp) {
      bf16x8 wf = *(const bf16x8*)((const char*)wp + (((fh*4 + tp)*4 + hh)*64 + lane)*16);
      pacc[tp] = mfma16(wf, ofr[hh], pacc[tp]);
    }

  float* ob = out + (size_t)b * 8192;
  #pragma unroll
  for (int tp = 0; tp < 4; ++tp) {
    float4 v;
    v.x = pacc[tp][0]; v.y = pacc[tp][1]; v.z = pacc[tp][2]; v.w = pacc[tp][3];
    // out[tok = mt*16+l15][f = (fh*4+tp)*16 + lq*4 + j]
    *(float4*)(ob + (mt*16 + l15)*128 + (fh*4 + tp)*16 + lq*4) = v;
  }
}

extern "C" void kernel_launch(void* const* d_in, const int* in_sizes, int n_in,
                              void* d_out, int out_size, void* d_ws, size_t ws_size,
                              hipStream_t stream) {
  const float* x        = (const float*)d_in[0];
  const float* qkv_w    = (const float*)d_in[1];
  const float* qkv_b    = (const float*)d_in[2];
  const float* proj_w   = (const float*)d_in[3];
  const float* proj_b   = (const float*)d_in[4];
  const float* bias_tab = (const float*)d_in[5];
  float* out = (float*)d_out;

  unsigned short* wq = (unsigned short*)d_ws;                      // 96 KB
  unsigned short* wp = (unsigned short*)((char*)d_ws + 98304);     // 32 KB
  float* bias_full   = (float*)((char*)d_ws + 131072);             // 64 KB

  int B = in_sizes[0] / 8192;   // (B, 64, 128)

  prep_kernel<<<320, 256, 0, stream>>>(qkv_w, proj_w, bias_tab, wq, wp, bias_full);
  fused_kernel<<<B, 512, 0, stream>>>(x, qkv_b, proj_b, wq, wp, bias_full, out);
}

// Round 9
// 126.247 us; speedup vs baseline: 1.7709x; 1.7709x over previous
//
#include <hip/hip_runtime.h>
#include <stdint.h>

// Fused Swin window attention for MI355X (gfx950) — R9 "two-pass QKV @ 6 waves/SIMD".
// B=4096 windows, N=64 tokens, C=128, H=4 heads, D=32.
// One block = one window; 512 threads = 8 waves; wave = (head h, token-half u).
// bf16 MFMA 16x16x32, f32 accum.
//
// Occupancy/spill frontier measured R7/R8: footprint ~96 unified regs ->
// (512,4)=clean/43%occ/130us, (512,8)=spill/84%occ/224us. R9 targets the
// missing point: (512,6) budget ~85, 3 blocks/CU = 24 waves/CU (75% cap).
// To fit 85, QKV is split: QK pass (32-reg acc) before S; V pass (16-reg acc)
// after softmax when S's 32 regs are dead. Phase peaks ~60-78 < 85.
//
// LDS (32 KB, rotating aliases; 5 barriers):
//   [0,16K):   x bf16 [64 tok][256B] swz (live through V pass) -> obuf
//              (O^T proj-B-frags [h][mt] x 1KB) after barrier 4
//   [16K,32K): kbuf K-frags [h][mt] x 1KB -> vbuf (V^T frags [h][u][dt] x 1KB)
//              after barrier 3
// Barriers: 1 x staged | 2 kbuf visible | 3 kbuf reads done (vbuf may alias)
//           | 4 vbuf visible + x reads done (obuf may alias) | 5 obuf visible.
// d_ws: wq bf16 @0 (96KB, Q-section pre-scaled by SCALE*log2e) |
//       wp bf16 @98304 (32KB) | bias_full f32 [H][64][64] @131072 (64KB, *log2e)

typedef __attribute__((ext_vector_type(4))) float        f32x4;
typedef __attribute__((ext_vector_type(8))) __bf16       bf16x8;
typedef __attribute__((ext_vector_type(4))) unsigned int u32x4;

#define DEV static __device__ __forceinline__

DEV unsigned short f2bf(float f) {          // f32 -> bf16 RNE (prep kernel only)
  unsigned int u = __float_as_uint(f);
  u += 0x7FFFu + ((u >> 16) & 1u);
  return (unsigned short)(u >> 16);
}

DEV unsigned int pk2(float a, float b) {    // packed bf16x2 via compiler casts
  __bf16 x = (__bf16)a, y = (__bf16)b;
  unsigned short ux = __builtin_bit_cast(unsigned short, x);
  unsigned short uy = __builtin_bit_cast(unsigned short, y);
  return (unsigned int)ux | ((unsigned int)uy << 16);
}

// Swizzled LDS byte address for x (XOR multiple of 16 keeps 16B alignment).
DEV int xaddr(int r, int cb) { return r*256 + (cb ^ ((r & 7) << 4)); }  // 256B rows

DEV f32x4 mfma16(bf16x8 a, bf16x8 b, f32x4 c) {
  return __builtin_amdgcn_mfma_f32_16x16x32_bf16(a, b, c, 0, 0, 0);
}

// In-register transpose (validated R3-R8): two C/D tiles of a 32-row x 16-col
// matrix M (t0 = rows 0..15, t1 = rows 16..31) -> fragment where lane (lq,l15)
// holds M[lq*8+i][l15], i=0..7, as bf16x8. Serves as B-frag of M (k=rows) and
// equally as A-frag of M^T.
DEV bf16x8 xpose(f32x4 t0, f32x4 t1, int idxA, int idxB, bool hi) {
  int a0 = (int)pk2(t0[0], t0[1]), a1 = (int)pk2(t0[2], t0[3]);
  int b0 = (int)pk2(t1[0], t1[1]), b1 = (int)pk2(t1[2], t1[3]);
  int w0A = __builtin_amdgcn_ds_bpermute(idxA, a0);
  int w0B = __builtin_amdgcn_ds_bpermute(idxA, b0);
  int w1A = __builtin_amdgcn_ds_bpermute(idxA, a1);
  int w1B = __builtin_amdgcn_ds_bpermute(idxA, b1);
  int w2A = __builtin_amdgcn_ds_bpermute(idxB, a0);
  int w2B = __builtin_amdgcn_ds_bpermute(idxB, b0);
  int w3A = __builtin_amdgcn_ds_bpermute(idxB, a1);
  int w3B = __builtin_amdgcn_ds_bpermute(idxB, b1);
  u32x4 u;
  u[0] = (unsigned)(hi ? w0B : w0A);
  u[1] = (unsigned)(hi ? w1B : w1A);
  u[2] = (unsigned)(hi ? w2B : w2A);
  u[3] = (unsigned)(hi ? w3B : w3A);
  return __builtin_bit_cast(bf16x8, u);
}

// Pack weights into the shared A/B fragment order; Q-section pre-scaled by
// SCALE*log2e; bias_full pre-scaled by log2e (softmax uses exp2 directly).
// Frag: lane l holds W[k=ks*32+(l>>4)*8+i][col=nt*16+(l&15)], i=0..7.
__global__ void prep_kernel(const float* __restrict__ qkv_w, const float* __restrict__ proj_w,
                            const float* __restrict__ bias_table,
                            unsigned short* __restrict__ wq, unsigned short* __restrict__ wp,
                            float* __restrict__ bias_full) {
  const float SCALE_LOG2E = 0.17677669529663687f * 1.4426950408889634f;
  const float LOG2E = 1.4426950408889634f;
  int idx = blockIdx.x * 256 + threadIdx.x;
  if (idx < 49152) {                                    // qkv_w (128 x 384)
    int i = idx & 7, lane = (idx >> 3) & 63, ks = (idx >> 9) & 3, nt = idx >> 11;
    int k = ks*32 + (lane >> 4)*8 + i;
    int col = nt*16 + (lane & 15);
    float v = qkv_w[k*384 + col];
    if (nt < 8) v *= SCALE_LOG2E;                       // Q section pre-scaled
    wq[idx] = f2bf(v);
  } else if (idx < 65536) {                             // proj_w (128 x 128)
    int t = idx - 49152;
    int i = t & 7, lane = (t >> 3) & 63, ks = (t >> 9) & 3, nt = t >> 11;
    int k = ks*32 + (lane >> 4)*8 + i;
    int col = nt*16 + (lane & 15);
    wp[t] = f2bf(proj_w[k*128 + col]);
  } else if (idx < 81920) {                             // bias_full[h][q][k] * log2e
    int t = idx - 65536;
    int h = t >> 12, q = (t >> 6) & 63, kk = t & 63;
    int ri = q >> 3, ci = q & 7, rj = kk >> 3, cj = kk & 7;
    bias_full[t] = bias_table[((ri - rj + 7)*15 + (ci - cj + 7))*4 + h] * LOG2E;
  }
}

__global__ __launch_bounds__(512, 6) void fused_kernel(
    const float* __restrict__ x, const float* __restrict__ qkv_b, const float* __restrict__ proj_b,
    const unsigned short* __restrict__ wq, const unsigned short* __restrict__ wp,
    const float* __restrict__ bias_full, float* __restrict__ out)
{
  __shared__ __align__(16) char lds[32768];
  const int b    = blockIdx.x;
  const int tid  = threadIdx.x;
  const int lane = tid & 63;
  const int w2   = tid >> 6;       // wave id 0..7
  const int h    = w2 >> 1;        // head
  const int u    = w2 & 1;         // token half (tokens u*32 .. u*32+31)
  const int l15  = lane & 15;
  const int lq   = lane >> 4;      // quarter-wave 0..3
  const float SCALE_LOG2E = 0.17677669529663687f * 1.4426950408889634f;
  const int  idxA = (((2*lq) & 3)*16 + l15) * 4;   // bpermute byte indices
  const int  idxB = idxA + 64;
  const bool hi   = lq >= 2;
  char* kbuf = lds + 16384;        // K frags; aliased by vbuf after barrier 3
  char* obuf = lds;                // O frags; aliases x after barrier 4

  // ---------- stage x -> [0,16K) as bf16 (swizzled) ----------
  {
    const float4* x4 = (const float4*)(x + (size_t)b * 8192);
    #pragma unroll
    for (int it = 0; it < 4; ++it) {
      int f4 = it*512 + tid;                 // 0..2047
      int r = f4 >> 5, c4 = f4 & 31;
      float4 v = x4[f4];
      *(uint2*)(lds + xaddr(r, c4*8)) = make_uint2(pk2(v.x, v.y), pk2(v.z, v.w));
    }
  }
  __syncthreads();                           // barrier 1

  // ---------- QK pass for this wave's 32 tokens (m-tiles 2u, 2u+1) ----------
  bf16x8 qf[2], kfl[2];
  {
    f32x4 qacc[2][2], kacc[2][2];
    #pragma unroll
    for (int t = 0; t < 2; ++t) {
      float4 bq = *(const float4*)(qkv_b +       h*32 + t*16 + lq*4);
      float4 bk = *(const float4*)(qkv_b + 128 + h*32 + t*16 + lq*4);
      f32x4 qi = {bq.x*SCALE_LOG2E, bq.y*SCALE_LOG2E, bq.z*SCALE_LOG2E, bq.w*SCALE_LOG2E};
      f32x4 ki = {bk.x, bk.y, bk.z, bk.w};
      #pragma unroll
      for (int i = 0; i < 2; ++i) { qacc[t][i] = qi; kacc[t][i] = ki; }
    }
    #pragma unroll 1                          // keep per-iteration liveness low
    for (int ks = 0; ks < 4; ++ks) {
      bf16x8 xfr[2];   // x[tok=(2u+i)*16+l15][c=ks*32+lq*8+i8]
      #pragma unroll
      for (int i = 0; i < 2; ++i)
        xfr[i] = *(const bf16x8*)(lds + xaddr((2*u + i)*16 + l15, ks*64 + lq*16));
      #pragma unroll
      for (int t = 0; t < 2; ++t) {
        bf16x8 wfq = *(const bf16x8*)((const char*)wq + (((2*h + t)*4     + ks)*64 + lane)*16);
        bf16x8 wfk = *(const bf16x8*)((const char*)wq + (((8 + 2*h + t)*4 + ks)*64 + lane)*16);
        #pragma unroll
        for (int i = 0; i < 2; ++i) {
          qacc[t][i] = mfma16(wfq, xfr[i], qacc[t][i]);   // Q^T tile (feat t, tok 2u+i)
          kacc[t][i] = mfma16(wfk, xfr[i], kacc[t][i]);   // K^T tile
        }
      }
    }
    #pragma unroll
    for (int i = 0; i < 2; ++i) {
      qf[i]  = xpose(qacc[0][i], qacc[1][i], idxA, idxB, hi);  // B-frag Q^T[d][q]
      kfl[i] = xpose(kacc[0][i], kacc[1][i], idxA, idxB, hi);  // A-frag K[key][d]
    }
  }

  // K frags -> kbuf (lane-linear b128, conflict-free)
  #pragma unroll
  for (int i = 0; i < 2; ++i)
    *(bf16x8*)(kbuf + (h*4 + 2*u + i)*1024 + lane*16) = kfl[i];
  __syncthreads();                           // barrier 2: kbuf visible (x still live)

  // ---------- S^T = K Q^T (all 64 keys x own 32 q), exp2 softmax, P frags ----------
  bf16x8 pf[2][2];   // [ks][m]: B-frag P^T, keys ks*32.., q-tile 2u+m
  float inv_[2];
  {
    bf16x8 kf[4];
    #pragma unroll
    for (int n = 0; n < 4; ++n)
      kf[n] = *(const bf16x8*)(kbuf + (h*4 + n)*1024 + lane*16);
    const float* bh = bias_full + h*4096;
    f32x4 s[4][2];   // tile (key n, q m): row=key=n*16+lq*4+j, col=q=(2u+m)*16+l15
    #pragma unroll
    for (int n = 0; n < 4; ++n)
      #pragma unroll
      for (int m = 0; m < 2; ++m) {
        float4 b4 = *(const float4*)(bh + ((2*u + m)*16 + l15)*64 + n*16 + lq*4);
        f32x4 si = {b4.x, b4.y, b4.z, b4.w};
        s[n][m] = mfma16(kf[n], qf[m], si);
      }
    // no-max softmax in base-2 (validated R3-R8); P unnormalized, 1/sum folded
    // into the O rescale.
    #pragma unroll
    for (int m = 0; m < 2; ++m) {
      float sum = 0.f;
      #pragma unroll
      for (int n = 0; n < 4; ++n)
        #pragma unroll
        for (int j = 0; j < 4; ++j) {
          float p = exp2f(s[n][m][j]);
          s[n][m][j] = p;
          sum += p;
        }
      sum += __shfl_xor(sum, 16);
      sum += __shfl_xor(sum, 32);
      inv_[m] = __fdividef(1.f, sum);
    }
    #pragma unroll
    for (int ks = 0; ks < 2; ++ks)
      #pragma unroll
      for (int m = 0; m < 2; ++m)
        pf[ks][m] = xpose(s[2*ks][m], s[2*ks + 1][m], idxA, idxB, hi);
  } // s dead — frees 32 regs before the V pass
  __syncthreads();                           // barrier 3: kbuf reads done -> vbuf may alias

  // ---------- V pass: V = x Wv (x still LDS-resident) ----------
  char* vbuf = kbuf;                         // aliases kbuf
  {
    f32x4 vacc[2][2];                        // tile (tok 2u+i, d dt)
    #pragma unroll
    for (int dt = 0; dt < 2; ++dt) {
      float bv = qkv_b[256 + h*32 + dt*16 + l15];
      #pragma unroll
      for (int i = 0; i < 2; ++i) vacc[i][dt] = (f32x4){bv, bv, bv, bv};
    }
    #pragma unroll 1
    for (int ks = 0; ks < 4; ++ks) {
      bf16x8 xfr[2];
      #pragma unroll
      for (int i = 0; i < 2; ++i)
        xfr[i] = *(const bf16x8*)(lds + xaddr((2*u + i)*16 + l15, ks*64 + lq*16));
      #pragma unroll
      for (int t = 0; t < 2; ++t) {
        bf16x8 wfv = *(const bf16x8*)((const char*)wq + (((16 + 2*h + t)*4 + ks)*64 + lane)*16);
        #pragma unroll
        for (int i = 0; i < 2; ++i)
          vacc[i][t] = mfma16(xfr[i], wfv, vacc[i][t]);
      }
    }
    // A-frags of V^T (toks u*32..+31) -> vbuf
    #pragma unroll
    for (int dt = 0; dt < 2; ++dt) {
      bf16x8 vfl = xpose(vacc[0][dt], vacc[1][dt], idxA, idxB, hi);
      *(bf16x8*)(vbuf + ((h*2 + u)*2 + dt)*1024 + lane*16) = vfl;
    }
  }
  __syncthreads();                           // barrier 4: vbuf visible, x reads done

  // ---------- O^T = V^T P^T (V frags from vbuf) ----------
  f32x4 o[2][2];   // tile (d dt, q m): row=d=dt*16+lq*4+j, col=q=(2u+m)*16+l15
  #pragma unroll
  for (int dt = 0; dt < 2; ++dt)
    #pragma unroll
    for (int m = 0; m < 2; ++m) o[dt][m] = (f32x4){0.f, 0.f, 0.f, 0.f};
  #pragma unroll
  for (int up = 0; up < 2; ++up) {           // key half = token half of V
    #pragma unroll
    for (int dt = 0; dt < 2; ++dt) {
      bf16x8 vf = *(const bf16x8*)(vbuf + ((h*2 + up)*2 + dt)*1024 + lane*16);
      #pragma unroll
      for (int m = 0; m < 2; ++m)
        o[dt][m] = mfma16(vf, pf[up][m], o[dt][m]);
    }
  }

  // rescale, xpose into proj B-frags -> obuf (aliases x; x dead after barrier 4)
  #pragma unroll
  for (int m = 0; m < 2; ++m) {
    f32x4 o0 = o[0][m], o1 = o[1][m];
    #pragma unroll
    for (int j = 0; j < 4; ++j) { o0[j] *= inv_[m]; o1[j] *= inv_[m]; }
    bf16x8 frg = xpose(o0, o1, idxA, idxB, hi);  // B-frag O^T: [ch=h*32+lq*8+i][q=l15]
    *(bf16x8*)(obuf + (h*4 + 2*u + m)*1024 + lane*16) = frg;
  }
  __syncthreads();                           // barrier 5: obuf visible

  // ---------- proj quarter: tokens (w2&3)*16.., features (w2>>2)*64.. ----------
  const int mt = w2 & 3;                     // token tile
  const int fh = w2 >> 2;                    // feature half
  bf16x8 ofr[4];
  #pragma unroll
  for (int hh = 0; hh < 4; ++hh)
    ofr[hh] = *(const bf16x8*)(obuf + (hh*4 + mt)*1024 + lane*16);

  f32x4 pacc[4];   // OUT^T tiles (feature fh*4+tp, tok tile mt)
  #pragma unroll
  for (int tp = 0; tp < 4; ++tp) {
    float4 pb4 = *(const float4*)(proj_b + (fh*4 + tp)*16 + lq*4);
    pacc[tp] = (f32x4){pb4.x, pb4.y, pb4.z, pb4.w};
  }
  #pragma unroll
  for (int hh = 0; hh < 4; ++hh)
    #pragma unroll
    for (int tp = 0; tp < 4; ++tp) {
      bf16x8 wf = *(const bf16x8*)((const char*)wp + (((fh*4 + tp)*4 + hh)*64 + lane)*16);
      pacc[tp] = mfma16(wf, ofr[hh], pacc[tp]);
    }

  float* ob = out + (size_t)b * 8192;
  #pragma unroll
  for (int tp = 0; tp < 4; ++tp) {
    float4 v;
    v.x = pacc[tp][0]; v.y = pacc[tp][1]; v.z = pacc[tp][2]; v.w = pacc[tp][3];
    // out[tok = mt*16+l15][f = (fh*4+tp)*16 + lq*4 + j]
    *(float4*)(ob + (mt*16 + l15)*128 + (fh*4 + tp)*16 + lq*4) = v;
  }
}

extern "C" void kernel_launch(void* const* d_in, const int* in_sizes, int n_in,
                              void* d_out, int out_size, void* d_ws, size_t ws_size,
                              hipStream_t stream) {
  const float* x        = (const float*)d_in[0];
  const float* qkv_w    = (const float*)d_in[1];
  const float* qkv_b    = (const float*)d_in[2];
  const float* proj_w   = (const float*)d_in[3];
  const float* proj_b   = (const float*)d_in[4];
  const float* bias_tab = (const float*)d_in[5];
  float* out = (float*)d_out;

  unsigned short* wq = (unsigned short*)d_ws;                      // 96 KB
  unsigned short* wp = (unsigned short*)((char*)d_ws + 98304);     // 32 KB
  float* bias_full   = (float*)((char*)d_ws + 131072);             // 64 KB

  int B = in_sizes[0] / 8192;   // (B, 64, 128)

  prep_kernel<<<320, 256, 0, stream>>>(qkv_w, proj_w, bias_tab, wq, wp, bias_full);
  fused_kernel<<<B, 512, 0, stream>>>(x, qkv_b, proj_b, wq, wp, bias_full, out);
}